// Round 4
// baseline (567.556 us; speedup 1.0000x reference)
//
#include <hip/hip_runtime.h>

// CRF log-likelihood, round 11: barrier-free scan — per-wave LDS sequence
// counters replace s_barrier (r10 evidence: 4-wave barrier 1216 cy/step ->
// 8-wave 1490 cy/step; barrier entry/wake dominates and phase-locks waves).
//
// Sync protocol: frags double-buffered (step s reads buf[(s-1)&1], writes
// buf[s&1]). Each wave, after its frag ds_write, drains own LDS
// (s_waitcnt lgkmcnt(0)) then publishes cnt[W4]=s (lane 0), then PREFETCHES
// all 4 counters for the next step. At step s a wave proceeds when
// min(cnt)>=s-1 (usually true from the prefetch -> zero sync latency;
// rare spin re-reads volatile). Overwrite hazard covered: writer of
// buf[s&1] at step s already verified partners >= s-1, i.e. their reads
// of that buffer (during their step s-1... s) are done two steps before
// the next overwrite. Consumer ordering safe: frag reads issue after the
// scalar branch consuming the counter value. fwd/bwd wave-sets de-phase
// and run independent iteration counts (no max-padding).
//
// Everything else as r10: one 512-thr block per group (waves 0-3 fwd,
// 4-7 bwd, 2 waves/SIMD now free to interleave), per wave 2 m-tiles,
// self-frag via C/D->B identity, 3 partner ds_read_b128, 8 MFMA
// (2x depth-2 chains), exp2 under MFMA shadow, 4-deep u prefetch ring,
// lag-1 renorm, bwd inj folded into fma. Blocks 16..79 do scores.

#define B_   256
#define LL   1024
#define TT   128
#define NBLK 16
#define L2E  1.4426950408889634f
#define LN2f 0.6931471805599453f

typedef __attribute__((ext_vector_type(8))) short bf16x8;
typedef __attribute__((ext_vector_type(4))) float f32x4;
union bfrw { unsigned w[4]; bf16x8 v; };

__device__ __forceinline__ unsigned bfround(float x) {   // RNE bf16 bits in [31:16]
    unsigned u = __float_as_uint(x);
    return u + 0x7fffu + ((u >> 16) & 1u);
}
__device__ __forceinline__ unsigned pack2(float lo, float hi) {  // [hi|lo] bf16 pair
#if __has_builtin(__builtin_amdgcn_cvt_pk_bf16_f32)
    auto p = __builtin_amdgcn_cvt_pk_bf16_f32(lo, hi);
    unsigned w; __builtin_memcpy(&w, &p, 4); return w;
#else
    return __builtin_amdgcn_perm(bfround(hi), bfround(lo), 0x07060302);
#endif
}

// fragls per set: [buf 0/1][cg 0..3][lane]x16B. Wave W4 writes cg=W4,
// keeps a register copy (bs), reads the other 3. af[m][i]: chain slot i ->
// cg {W4, c1, c2, c3} (others ascending).

template<bool FWD, int PH>
__device__ __forceinline__ void phase(int t, int s, float& Dacc,
                                      float4 (&up)[4][2],
                                      const bf16x8 (&af)[2][4],
                                      bf16x8& bs,
                                      short* fset, float* sb2, int* cnts,
                                      int4& cpre,
                                      const float* pu,
                                      float* cl, float* dc,
                                      int o0, int o1, int o2, int ws,
                                      int cb, int tfin, int W4, int q, int b,
                                      int lane)
{
    constexpr int CUR  = PH & 1;        // == (s-1)&1 (s = 4i+1+PH)
    constexpr int NXT  = CUR ^ 1;
    constexpr int SLOT = FWD ? ((1 + PH) & 3) : ((3 - PH) & 3);

    // ---- sync: partners must have finished step s-1 (prefetched check) ----
    {
        const int need = s - 1;
        int mn0 = cpre.x < cpre.y ? cpre.x : cpre.y;
        int mn1 = cpre.z < cpre.w ? cpre.z : cpre.w;
        int mn  = mn0 < mn1 ? mn0 : mn1;
        while (mn < need) {                       // rare path
            volatile const int* vc = (volatile const int*)cnts;
            int a0 = vc[0], a1 = vc[1], a2 = vc[2], a3 = vc[3];
            mn0 = a0 < a1 ? a0 : a1;
            mn1 = a2 < a3 ? a2 : a3;
            mn  = mn0 < mn1 ? mn0 : mn1;
        }
    }

    // partner frags (slots 1..3) + lag-1 scale from LDS buf CUR
    bf16x8 bo0 = *(const bf16x8*)(fset + CUR * 2048 + o0);
    bf16x8 bo1 = *(const bf16x8*)(fset + CUR * 2048 + o1);
    bf16x8 bo2 = *(const bf16x8*)(fset + CUR * 2048 + o2);
    float sprev = sb2[CUR * 16 + b];

    // ---- 8 MFMA: 2 m-tiles x 2 depth-2 chains, self slot issues first ----
    f32x4 ae0, ae1, ao0, ao1;
    ae0 = __builtin_amdgcn_mfma_f32_16x16x32_bf16(af[0][0], bs,  (f32x4){0.f,0.f,0.f,0.f}, 0, 0, 0);
    ae1 = __builtin_amdgcn_mfma_f32_16x16x32_bf16(af[1][0], bs,  (f32x4){0.f,0.f,0.f,0.f}, 0, 0, 0);
    ao0 = __builtin_amdgcn_mfma_f32_16x16x32_bf16(af[0][1], bo0, (f32x4){0.f,0.f,0.f,0.f}, 0, 0, 0);
    ao1 = __builtin_amdgcn_mfma_f32_16x16x32_bf16(af[1][1], bo0, (f32x4){0.f,0.f,0.f,0.f}, 0, 0, 0);
    ae0 = __builtin_amdgcn_mfma_f32_16x16x32_bf16(af[0][2], bo1, ae0, 0, 0, 0);
    ae1 = __builtin_amdgcn_mfma_f32_16x16x32_bf16(af[1][2], bo1, ae1, 0, 0, 0);
    ao0 = __builtin_amdgcn_mfma_f32_16x16x32_bf16(af[0][3], bo2, ao0, 0, 0, 0);
    ao1 = __builtin_amdgcn_mfma_f32_16x16x32_bf16(af[1][3], bo2, ao1, 0, 0, 0);

    // u from ring; exp2 issues under MFMA latency (trans pipe)
    float ex[2][4];
    #pragma unroll
    for (int m = 0; m < 2; ++m) {
        float4 v = up[SLOT][m];
        ex[m][0] = __builtin_amdgcn_exp2f(v.x * L2E);
        ex[m][1] = __builtin_amdgcn_exp2f(v.y * L2E);
        ex[m][2] = __builtin_amdgcn_exp2f(v.z * L2E);
        ex[m][3] = __builtin_amdgcn_exp2f(v.w * L2E);
    }
    {   // prefetch into the freed slot (consumed 4 steps later)
        int tp = FWD ? (t + 4) : (t - 5);
        tp = tp < 0 ? 0 : (tp > LL - 1 ? LL - 1 : tp);
        const float* pt = pu + (size_t)tp * TT;
        up[SLOT][0] = *(const float4*)(pt);
        up[SLOT][1] = *(const float4*)(pt + 16);
    }

    // lag-1 renorm scalars (uniform per batch column b)
    float ci = __builtin_amdgcn_rcpf(sprev);
    float lg = __builtin_amdgcn_logf(sprev);          // v_log_f32 = log2
    bool inj = (!FWD) && (tfin == t - 1);
    float cis  = inj ? 0.f : ci;
    float injf = inj ? 1.f : 0.f;
    Dacc = inj ? 0.f : (Dacc + lg);

    f32x4 a0 = ae0 + ao0;
    f32x4 a1 = ae1 + ao1;

    float rv[2][4];
    #pragma unroll
    for (int r = 0; r < 4; ++r) {
        rv[0][r] = cis * a0[r] + injf;                // inj folded into fma
        rv[1][r] = cis * a1[r] + injf;
    }

    if (!FWD) {
        bool cap = (cb == t - 1) && (cb != tfin);     // cap => !inj
        if (__any(cap)) {
            if (cap) {
                float4 c0 = {rv[0][0], rv[0][1], rv[0][2], rv[0][3]};
                float4 c1 = {rv[1][0], rv[1][1], rv[1][2], rv[1][3]};
                *(float4*)(cl + b * TT + 32 * W4 + q * 4)      = c0;
                *(float4*)(cl + b * TT + 32 * W4 + 16 + q * 4) = c1;
                if (W4 == 0 && q == 0) dc[b] = Dacc;
            }
        }
    }

    float ov[2][4];
    #pragma unroll
    for (int r = 0; r < 4; ++r) {
        ov[0][r] = ex[0][r] * rv[0][r];
        ov[1][r] = ex[1][r] * rv[1][r];
    }

    if (FWD) {
        bool cap = (cb == t);
        if (__any(cap)) {
            if (cap) {
                float4 c0 = {ov[0][0], ov[0][1], ov[0][2], ov[0][3]};
                float4 c1 = {ov[1][0], ov[1][1], ov[1][2], ov[1][3]};
                *(float4*)(cl + b * TT + 32 * W4 + q * 4)      = c0;
                *(float4*)(cl + b * TT + 32 * W4 + 16 + q * 4) = c1;
                if (W4 == 0 && q == 0) dc[b] = Dacc;
            }
        }
    }

    // raw S0 for next step's renorm: global row 0 = wave 0, m=0, q=0, reg 0
    if (W4 == 0 && q == 0) sb2[NXT * 16 + b] = a0[0];

    // pack self next-state frag (identity: frag W4 <- m-tiles {0,1} here)
    bfrw pk;
    pk.w[0] = pack2(ov[0][0], ov[0][1]);
    pk.w[1] = pack2(ov[0][2], ov[0][3]);
    pk.w[2] = pack2(ov[1][0], ov[1][1]);
    pk.w[3] = pack2(ov[1][2], ov[1][3]);
    bs = pk.v;
    *(bf16x8*)(fset + NXT * 2048 + ws) = pk.v;

    // drain own LDS writes, publish step s, prefetch counters for s+1
    asm volatile("s_waitcnt lgkmcnt(0)" ::: "memory");
    if (lane == 0) *(volatile int*)(cnts + W4) = s;
    {
        volatile const int* vc = (volatile const int*)cnts;
        cpre.x = vc[0]; cpre.y = vc[1]; cpre.z = vc[2]; cpre.w = vc[3];
    }
}

__launch_bounds__(512, 1)
__global__ void crf_scan(const float* __restrict__ inputs,
                         const int*   __restrict__ tags,
                         const int*   __restrict__ slens,
                         const float* __restrict__ trans,
                         float* __restrict__ qcap, float* __restrict__ rcap,
                         float* __restrict__ dqv,  float* __restrict__ drv,
                         int* __restrict__ perm, float* __restrict__ scorebuf)
{
    __shared__ __align__(16) short fragls[2][2][4][64 * 8];   // 16 KB
    __shared__ __align__(16) float capl[2][16][TT];           // 16 KB
    __shared__ __align__(16) int cnt[2][4];                   // seq counters
    __shared__ float dcap[2][16];
    __shared__ float sbuf[2][2][16];
    __shared__ float ssb[8];
    __shared__ int keys[B_];

    const int tid = threadIdx.x;

    // ---------------- score blocks (16..79): 4 batches each ----------------
    if (blockIdx.x >= NBLK) {
        const int sbid = blockIdx.x - NBLK;         // 0..63
        const int lane = tid & 63, w = tid >> 6;
        #pragma unroll 1
        for (int bi = 0; bi < 4; ++bi) {
            const int b = sbid * 4 + bi;
            const int slen = slens[b];
            const float* inb  = inputs + (size_t)b * LL * TT;
            const int*   tagb = tags + b * LL;
            float sc = 0.f;
            for (int t = tid; t < slen; t += 512) {
                int tg = tagb[t];
                float v = inb[(size_t)t * TT + tg];
                if (t >= 1) v += trans[tagb[t - 1] * TT + tg];
                sc += v;
            }
            #pragma unroll
            for (int off = 32; off > 0; off >>= 1) sc += __shfl_xor(sc, off, 64);
            if (lane == 0) ssb[w] = sc;
            __syncthreads();
            if (tid == 0) scorebuf[b] = ssb[0] + ssb[1] + ssb[2] + ssb[3]
                                      + ssb[4] + ssb[5] + ssb[6] + ssb[7];
            __syncthreads();
        }
        return;
    }

    // ---------------- merged scan blocks (0..15) ----------------
    const int g = blockIdx.x;

    // deterministic bitonic sort of (slen, batch) keys (256 keys, 512 thr)
    if (tid < 256) keys[tid] = slens[tid] * 256 + tid;
    if (tid < 8) cnt[tid >> 2][tid & 3] = 0;        // "step 0 done"
    __syncthreads();
    for (int k = 2; k <= B_; k <<= 1) {
        for (int s = k >> 1; s > 0; s >>= 1) {
            if (tid < 256) {
                int ixj = tid ^ s;
                if (ixj > tid) {
                    int a = keys[tid], b2 = keys[ixj];
                    bool asc = ((tid & k) == 0);
                    if ((a > b2) == asc) { keys[tid] = b2; keys[ixj] = a; }
                }
            }
            __syncthreads();
        }
    }
    if (tid < 16) perm[g * 16 + tid] = keys[g * 16 + tid] & 255;

    const int set  = tid >> 8;                  // 0 = fwd, 1 = bwd
    const bool isf = (set == 0);
    const int lane = tid & 63;
    const int W4   = __builtin_amdgcn_readfirstlane((tid >> 6) & 3);
    const int q    = lane >> 4;
    const int b    = lane & 15;

    const int key = keys[g * 16 + b];
    const int ob  = key & 255;
    const int sl  = key >> 8;
    int tfin = sl - 1; if (tfin < 1) tfin = 1;

    int tmax = tfin;
    #pragma unroll
    for (int o = 1; o < 16; o <<= 1) {
        int c2 = __shfl_xor(tmax, o, 16); tmax = c2 > tmax ? c2 : tmax;
    }
    tmax = __builtin_amdgcn_readfirstlane(tmax);

    const int C  = (tmax + 4) >> 1;             // balanced cut (>=2)
    const int cb = tfin < C ? tfin : C;

    int cmax = cb, cmin = cb;
    #pragma unroll
    for (int o = 1; o < 16; o <<= 1) {
        int a = __shfl_xor(cmax, o, 16); cmax = a > cmax ? a : cmax;
        int b2 = __shfl_xor(cmin, o, 16); cmin = b2 < cmin ? b2 : cmin;
    }
    cmax = __builtin_amdgcn_readfirstlane(cmax);
    cmin = __builtin_amdgcn_readfirstlane(cmin);

    const int tb0 = (tmax + 4) & ~3;            // bwd start, == 0 mod 4
    const int nif = (cmax + 3) >> 2;            // fwd iterations (own count)
    const int nib = (tb0 - cmin + 3) >> 2;      // bwd iterations (own count)

    // slot -> cg mapping: {W4, others ascending}
    const int c1 = (W4 == 0) ? 1 : 0;
    const int c2 = (W4 <= 1) ? 2 : 1;
    const int c3 = (W4 <= 2) ? 3 : 2;
    const int o0 = (c1 * 64 + lane) * 8;
    const int o1 = (c2 * 64 + lane) * 8;
    const int o2 = (c3 * 64 + lane) * 8;
    const int ws = (W4 * 64 + lane) * 8;

    // E fragments: af[m][i], slot i -> cg {W4,c1,c2,c3};
    // j = 32*W4 + 16m + b; k = 32c + 16*(jj>>2) + 4q + (jj&3) (verified)
    bf16x8 af[2][4];
    #pragma unroll
    for (int m = 0; m < 2; ++m) {
        const int j = 32 * W4 + 16 * m + b;
        #pragma unroll
        for (int i = 0; i < 4; ++i) {
            const int c = (i == 0) ? W4 : (i == 1) ? c1 : (i == 2) ? c2 : c3;
            #pragma unroll
            for (int jj = 0; jj < 8; ++jj) {
                int k = 32 * c + 16 * (jj >> 2) + 4 * q + (jj & 3);
                int idx = isf ? (k * TT + j) : (j * TT + k);
                float ev = __builtin_amdgcn_exp2f(trans[idx] * L2E);
                af[m][i][jj] = (short)(bfround(ev) >> 16);
            }
        }
    }

    short* fset = &fragls[set][0][0][0];
    float* sb2  = &sbuf[set][0][0];
    float* cl   = &capl[set][0][0];
    float* dc   = &dcap[set][0];
    int*   cnts = &cnt[set][0];

    const float* pu = inputs + (size_t)ob * LL * TT + 32 * W4 + q * 4;
    float Dacc = 0.f;
    float4 up[4][2];
    bf16x8 bs;
    int4 cpre = {0, 0, 0, 0};                   // counters known 0 at start

    if (W4 == 0 && lane < 16) sb2[lane] = 1.0f; // initial scale (buf 0)

    if (isf) {
        // init q0 = exp(in[0][j]) -> self frag + LDS buf0 (cb>=1: no init cap)
        float q0[2][4];
        #pragma unroll
        for (int m = 0; m < 2; ++m) {
            float4 v = *(const float4*)(pu + m * 16);
            q0[m][0] = __builtin_amdgcn_exp2f(v.x * L2E);
            q0[m][1] = __builtin_amdgcn_exp2f(v.y * L2E);
            q0[m][2] = __builtin_amdgcn_exp2f(v.z * L2E);
            q0[m][3] = __builtin_amdgcn_exp2f(v.w * L2E);
        }
        bfrw pk;
        pk.w[0] = pack2(q0[0][0], q0[0][1]);
        pk.w[1] = pack2(q0[0][2], q0[0][3]);
        pk.w[2] = pack2(q0[1][0], q0[1][1]);
        pk.w[3] = pack2(q0[1][2], q0[1][3]);
        bs = pk.v;
        *(bf16x8*)(fset + ws) = pk.v;

        #pragma unroll
        for (int s = 1; s <= 4; ++s) {
            up[s & 3][0] = *(const float4*)(pu + (size_t)s * TT);
            up[s & 3][1] = *(const float4*)(pu + (size_t)s * TT + 16);
        }
    } else {
        // init w = 1.0; batches with cb == tfin capture ones / Dr = 0 here
        bfrw pk;
        pk.w[0] = pk.w[1] = pk.w[2] = pk.w[3] = 0x3F803F80u;
        bs = pk.v;
        *(bf16x8*)(fset + ws) = pk.v;
        if (cb == tfin) {
            float4 one4 = {1.f, 1.f, 1.f, 1.f};
            *(float4*)(cl + b * TT + 32 * W4 + q * 4)      = one4;
            *(float4*)(cl + b * TT + 32 * W4 + 16 + q * 4) = one4;
            if (W4 == 0 && q == 0) dc[b] = 0.f;
        }
        #pragma unroll
        for (int ph = 0; ph < 4; ++ph) {
            int ui = tb0 - 1 - ph;
            ui = ui > LL - 1 ? LL - 1 : (ui < 0 ? 0 : ui);
            up[(3 - ph) & 3][0] = *(const float4*)(pu + (size_t)ui * TT);
            up[(3 - ph) & 3][1] = *(const float4*)(pu + (size_t)ui * TT + 16);
        }
    }
    __syncthreads();    // init frags + counters visible; loops run free now

    if (isf) {
        for (int i = 0; i < nif; ++i) {
            const int tb = 1 + 4 * i;   // s == t for fwd
            phase<true,0>(tb+0, tb+0, Dacc, up, af, bs, fset, sb2, cnts, cpre, pu, cl, dc, o0,o1,o2,ws, cb, tfin, W4, q, b, lane);
            phase<true,1>(tb+1, tb+1, Dacc, up, af, bs, fset, sb2, cnts, cpre, pu, cl, dc, o0,o1,o2,ws, cb, tfin, W4, q, b, lane);
            phase<true,2>(tb+2, tb+2, Dacc, up, af, bs, fset, sb2, cnts, cpre, pu, cl, dc, o0,o1,o2,ws, cb, tfin, W4, q, b, lane);
            phase<true,3>(tb+3, tb+3, Dacc, up, af, bs, fset, sb2, cnts, cpre, pu, cl, dc, o0,o1,o2,ws, cb, tfin, W4, q, b, lane);
        }
    } else {
        for (int i = 0; i < nib; ++i) {
            const int tb = tb0 - 4 * i;
            const int s0 = 4 * i + 1;
            phase<false,0>(tb-0, s0+0, Dacc, up, af, bs, fset, sb2, cnts, cpre, pu, cl, dc, o0,o1,o2,ws, cb, tfin, W4, q, b, lane);
            phase<false,1>(tb-1, s0+1, Dacc, up, af, bs, fset, sb2, cnts, cpre, pu, cl, dc, o0,o1,o2,ws, cb, tfin, W4, q, b, lane);
            phase<false,2>(tb-2, s0+2, Dacc, up, af, bs, fset, sb2, cnts, cpre, pu, cl, dc, o0,o1,o2,ws, cb, tfin, W4, q, b, lane);
            phase<false,3>(tb-3, s0+3, Dacc, up, af, bs, fset, sb2, cnts, cpre, pu, cl, dc, o0,o1,o2,ws, cb, tfin, W4, q, b, lane);
        }
    }

    __syncthreads();    // captures from both sets visible

    // copy captures out
    float* gout = isf ? qcap : rcap;
    const int ltid = tid & 255;
    #pragma unroll
    for (int i = 0; i < 2; ++i) {
        float4 v = *(const float4*)(cl + i * 1024 + ltid * 4);
        *(float4*)(gout + (size_t)g * 16 * TT + i * 1024 + ltid * 4) = v;
    }
    if (ltid < 16) (isf ? dqv : drv)[g * 16 + ltid] = dc[ltid];
}

__global__ void crf_comb(const float* __restrict__ qcap, const float* __restrict__ rcap,
                         const float* __restrict__ dqv, const float* __restrict__ drv,
                         const int* __restrict__ perm, const float* __restrict__ scorebuf,
                         float* __restrict__ out) {
    const int tid = threadIdx.x;
    const int r16 = tid >> 4, part = tid & 15;
    const int rank = blockIdx.x * 16 + r16;
    const float* qc = qcap + rank * TT + part * 8;
    const float* rc = rcap + rank * TT + part * 8;
    float4 a0 = *(const float4*)(qc);
    float4 a1 = *(const float4*)(qc + 4);
    float4 b0 = *(const float4*)(rc);
    float4 b1 = *(const float4*)(rc + 4);
    float s = a0.x*b0.x + a0.y*b0.y + a0.z*b0.z + a0.w*b0.w
            + a1.x*b1.x + a1.y*b1.y + a1.z*b1.z + a1.w*b1.w;
    #pragma unroll
    for (int o = 1; o < 16; o <<= 1) s += __shfl_xor(s, o, 16);
    if (part == 0) {
        int ob = perm[rank];
        float logZ = LN2f * (__builtin_amdgcn_logf(s) + dqv[rank] + drv[rank]);
        out[ob] = scorebuf[ob] - logZ;
    }
}

extern "C" void kernel_launch(void* const* d_in, const int* in_sizes, int n_in,
                              void* d_out, int out_size, void* d_ws, size_t ws_size,
                              hipStream_t stream) {
    const float* inputs = (const float*)d_in[0];
    const int*   tags   = (const int*)d_in[1];
    const int*   slens  = (const int*)d_in[2];
    const float* trans  = (const float*)d_in[3];
    float* out = (float*)d_out;

    float* qcap = (float*)d_ws;            // 256*128 f32
    float* rcap = qcap + 32768;            // 256*128 f32
    float* dqv  = rcap + 32768;            // 256
    float* drv  = dqv + 256;               // 256
    int*   perm = (int*)(drv + 256);       // 256
    float* scorebuf = (float*)(perm + 256);// 256

    crf_scan<<<NBLK + 64, 512, 0, stream>>>(inputs, tags, slens, trans,
                                            qcap, rcap, dqv, drv, perm, scorebuf);
    crf_comb<<<NBLK, 256, 0, stream>>>(qcap, rcap, dqv, drv, perm, scorebuf, out);
}

// Round 5
// 411.275 us; speedup vs baseline: 1.3800x; 1.3800x over previous
//
#include <hip/hip_runtime.h>

// CRF log-likelihood, round 12: r7's proven skeleton (4-wave scan blocks,
// separate fwd/bwd blocks, s_barrier) + the C/D->B self-fragment identity
// (verified in r8/r10): each wave keeps its own next-step B-fragment in
// registers, so slot-0 MFMAs issue at barrier-exit with no LDS latency and
// the exchange is 3 ds_read_b128 + 1 ds_write_b128 per wave per step.
//
// Identity: mfma_f32_16x16x32_bf16 C/D row = 4*(lane>>4)+reg, col = lane&15;
// B-frag k = 32c + 16*(jj>>2) + 4*(lane>>4) + (jj&3), col = lane&15. Wave W
// owns rows 32W..32W+31 (m-tiles {2W,2W+1}) == k-chunk c=W of the next state:
// pack2(ov) is bit-for-bit its own slot-0 B operand.
//
// crf_scan grid = 96 blocks x 256 thr:
//   blocks 0..15  : FORWARD scan, t = 1..cmax, capture q_cb.
//   blocks 16..31 : BACKWARD scan r_{t-1} = E(u_t.*r_t), t = tb0..cmin+1,
//                   capture r_cb; cb==tfin batches capture ones at init.
//   blocks 32..95 : unary+binary scores (4 batches each), concurrent.
// Per wave/step: 3 partner ds_read_b128 + 1 sb read, 8 MFMA (2 m-tiles x
// depth-2 chains, self slot first), 8 exp2 under MFMA shadow, 4-deep u
// prefetch ring (2 global_load_dwordx4), lag-1 renorm c = rcp(S0_prev) with
// exact Dacc (log2), bwd inj folded into fma, pack via v_cvt_pk_bf16_f32,
// barrier = s_waitcnt lgkmcnt(0); s_barrier.
// crf_comb: logZ = ln2*(log2(dot(qcap,rcap)) + Dq + Dr); out = score - logZ.

#define B_   256
#define LL   1024
#define TT   128
#define NBLK 16
#define L2E  1.4426950408889634f
#define LN2f 0.6931471805599453f

typedef __attribute__((ext_vector_type(8))) short bf16x8;
typedef __attribute__((ext_vector_type(4))) float f32x4;
union bfrw { unsigned w[4]; bf16x8 v; };

__device__ __forceinline__ unsigned bfround(float x) {   // RNE bf16 bits in [31:16]
    unsigned u = __float_as_uint(x);
    return u + 0x7fffu + ((u >> 16) & 1u);
}
__device__ __forceinline__ unsigned pack2(float lo, float hi) {  // [hi|lo] bf16 pair
#if __has_builtin(__builtin_amdgcn_cvt_pk_bf16_f32)
    auto p = __builtin_amdgcn_cvt_pk_bf16_f32(lo, hi);
    unsigned w; __builtin_memcpy(&w, &p, 4); return w;
#else
    return __builtin_amdgcn_perm(bfround(hi), bfround(lo), 0x07060302);
#endif
}
__device__ __forceinline__ void lds_barrier() {
    asm volatile("s_waitcnt lgkmcnt(0)\n\ts_barrier" ::: "memory");
}

// fragls: [buf 0/1][cg 0..3][lane 0..63] x 16B. Wave W writes cg=W (its
// packed next-state frag), keeps a register copy (bs), reads the other 3.
// af[m][i]: chain slot i -> cg {W, c1, c2, c3} (others ascending).

template<bool FWD, int PH>
__device__ __forceinline__ void phase(int t, float& Dacc,
                                      float4 (&up)[4][2],
                                      const bf16x8 (&af)[2][4],
                                      bf16x8& bs,
                                      short* fragls, float* sbuf,
                                      const float* pu,
                                      float* capl, float* dcap,
                                      int o0, int o1, int o2, int ws,
                                      int cb, int tfin, int W, int q, int b)
{
    constexpr int CUR  = PH & 1;
    constexpr int NXT  = CUR ^ 1;
    constexpr int SLOT = FWD ? ((1 + PH) & 3) : ((3 - PH) & 3);

    // partner frags (slots 1..3) + lag-1 scale from LDS buf CUR
    bf16x8 bo0 = *(const bf16x8*)(fragls + CUR * 2048 + o0);
    bf16x8 bo1 = *(const bf16x8*)(fragls + CUR * 2048 + o1);
    bf16x8 bo2 = *(const bf16x8*)(fragls + CUR * 2048 + o2);
    float sprev = sbuf[CUR * 16 + b];

    // ---- 8 MFMA: 2 m-tiles x 2 depth-2 chains; self slot (register-fed)
    // issues first so the partner ds_read latency hides under it ----
    f32x4 ae0, ae1, ao0, ao1;
    ae0 = __builtin_amdgcn_mfma_f32_16x16x32_bf16(af[0][0], bs,  (f32x4){0.f,0.f,0.f,0.f}, 0, 0, 0);
    ae1 = __builtin_amdgcn_mfma_f32_16x16x32_bf16(af[1][0], bs,  (f32x4){0.f,0.f,0.f,0.f}, 0, 0, 0);
    ao0 = __builtin_amdgcn_mfma_f32_16x16x32_bf16(af[0][1], bo0, (f32x4){0.f,0.f,0.f,0.f}, 0, 0, 0);
    ao1 = __builtin_amdgcn_mfma_f32_16x16x32_bf16(af[1][1], bo0, (f32x4){0.f,0.f,0.f,0.f}, 0, 0, 0);
    ae0 = __builtin_amdgcn_mfma_f32_16x16x32_bf16(af[0][2], bo1, ae0, 0, 0, 0);
    ae1 = __builtin_amdgcn_mfma_f32_16x16x32_bf16(af[1][2], bo1, ae1, 0, 0, 0);
    ao0 = __builtin_amdgcn_mfma_f32_16x16x32_bf16(af[0][3], bo2, ao0, 0, 0, 0);
    ao1 = __builtin_amdgcn_mfma_f32_16x16x32_bf16(af[1][3], bo2, ao1, 0, 0, 0);

    // u from ring; exp2 issues under MFMA latency (trans pipe)
    float ex[2][4];
    #pragma unroll
    for (int m = 0; m < 2; ++m) {
        float4 v = up[SLOT][m];
        ex[m][0] = __builtin_amdgcn_exp2f(v.x * L2E);
        ex[m][1] = __builtin_amdgcn_exp2f(v.y * L2E);
        ex[m][2] = __builtin_amdgcn_exp2f(v.z * L2E);
        ex[m][3] = __builtin_amdgcn_exp2f(v.w * L2E);
    }
    {   // prefetch into the freed slot (consumed 4 steps later)
        int tp = FWD ? (t + 4) : (t - 5);
        tp = tp < 0 ? 0 : (tp > LL - 1 ? LL - 1 : tp);
        const float* pt = pu + (size_t)tp * TT;
        up[SLOT][0] = *(const float4*)(pt);
        up[SLOT][1] = *(const float4*)(pt + 16);
    }

    // lag-1 renorm scalars (uniform per batch column b)
    float ci = __builtin_amdgcn_rcpf(sprev);
    float lg = __builtin_amdgcn_logf(sprev);          // v_log_f32 = log2
    bool inj = (!FWD) && (tfin == t - 1);
    float cis  = inj ? 0.f : ci;
    float injf = inj ? 1.f : 0.f;
    Dacc = inj ? 0.f : (Dacc + lg);

    f32x4 a0 = ae0 + ao0;
    f32x4 a1 = ae1 + ao1;

    float rv[2][4];
    #pragma unroll
    for (int r = 0; r < 4; ++r) {
        rv[0][r] = cis * a0[r] + injf;                // inj folded into fma
        rv[1][r] = cis * a1[r] + injf;
    }

    if (!FWD) {
        bool cap = (cb == t - 1) && (cb != tfin);     // cap => !inj
        if (__any(cap)) {
            if (cap) {
                float4 c0 = {rv[0][0], rv[0][1], rv[0][2], rv[0][3]};
                float4 c1 = {rv[1][0], rv[1][1], rv[1][2], rv[1][3]};
                *(float4*)(capl + b * TT + 32 * W + q * 4)      = c0;
                *(float4*)(capl + b * TT + 32 * W + 16 + q * 4) = c1;
                if (W == 0 && q == 0) dcap[b] = Dacc;
            }
        }
    }

    float ov[2][4];
    #pragma unroll
    for (int r = 0; r < 4; ++r) {
        ov[0][r] = ex[0][r] * rv[0][r];
        ov[1][r] = ex[1][r] * rv[1][r];
    }

    if (FWD) {
        bool cap = (cb == t);
        if (__any(cap)) {
            if (cap) {
                float4 c0 = {ov[0][0], ov[0][1], ov[0][2], ov[0][3]};
                float4 c1 = {ov[1][0], ov[1][1], ov[1][2], ov[1][3]};
                *(float4*)(capl + b * TT + 32 * W + q * 4)      = c0;
                *(float4*)(capl + b * TT + 32 * W + 16 + q * 4) = c1;
                if (W == 0 && q == 0) dcap[b] = Dacc;
            }
        }
    }

    // raw S0 for next step's renorm: global row 0 = wave 0, m=0, q=0, reg 0
    if (W == 0 && q == 0) sbuf[NXT * 16 + b] = a0[0];

    // pack self next-state frag (identity: frag W <- m-tiles {2W, 2W+1})
    bfrw pk;
    pk.w[0] = pack2(ov[0][0], ov[0][1]);
    pk.w[1] = pack2(ov[0][2], ov[0][3]);
    pk.w[2] = pack2(ov[1][0], ov[1][1]);
    pk.w[3] = pack2(ov[1][2], ov[1][3]);
    bs = pk.v;
    *(bf16x8*)(fragls + NXT * 2048 + ws) = pk.v;

    lds_barrier();
}

__launch_bounds__(256, 1)
__global__ void crf_scan(const float* __restrict__ inputs,
                         const int*   __restrict__ tags,
                         const int*   __restrict__ slens,
                         const float* __restrict__ trans,
                         float* __restrict__ qcap, float* __restrict__ rcap,
                         float* __restrict__ dqv,  float* __restrict__ drv,
                         int* __restrict__ perm, float* __restrict__ scorebuf)
{
    __shared__ __align__(16) short fragls[2 * 4 * 64 * 8];   // 8 KB exchange
    __shared__ __align__(16) float capl[16 * TT];            // 8 KB captures
    __shared__ float dcap[16];
    __shared__ float sbuf[2 * 16];
    __shared__ float ssb[4];
    __shared__ int keys[B_];

    const int tid = threadIdx.x;

    // ---------------- score blocks (32..95): 4 batches each ----------------
    if (blockIdx.x >= 2 * NBLK) {
        const int sbid = blockIdx.x - 2 * NBLK;     // 0..63
        const int lane = tid & 63, w = tid >> 6;
        #pragma unroll 1
        for (int bi = 0; bi < 4; ++bi) {
            const int b = sbid * 4 + bi;
            const int slen = slens[b];
            const float* inb  = inputs + (size_t)b * LL * TT;
            const int*   tagb = tags + b * LL;
            float sc = 0.f;
            for (int t = tid; t < slen; t += 256) {
                int tg = tagb[t];
                float v = inb[(size_t)t * TT + tg];
                if (t >= 1) v += trans[tagb[t - 1] * TT + tg];
                sc += v;
            }
            #pragma unroll
            for (int off = 32; off > 0; off >>= 1) sc += __shfl_xor(sc, off, 64);
            if (lane == 0) ssb[w] = sc;
            __syncthreads();
            if (tid == 0) scorebuf[b] = ssb[0] + ssb[1] + ssb[2] + ssb[3];
            __syncthreads();
        }
        return;
    }

    // ---------------- scan blocks (0..31) ----------------
    // deterministic bitonic sort of (slen, batch) keys — identical all blocks
    keys[tid] = slens[tid] * 256 + tid;
    __syncthreads();
    for (int k = 2; k <= B_; k <<= 1) {
        for (int s = k >> 1; s > 0; s >>= 1) {
            int ixj = tid ^ s;
            if (ixj > tid) {
                int a = keys[tid], b2 = keys[ixj];
                bool asc = ((tid & k) == 0);
                if ((a > b2) == asc) { keys[tid] = b2; keys[ixj] = a; }
            }
            __syncthreads();
        }
    }

    const bool isf = (blockIdx.x < NBLK);
    const int g    = isf ? blockIdx.x : blockIdx.x - NBLK;
    if (isf && tid < 16) perm[g * 16 + tid] = keys[g * 16 + tid] & 255;

    const int lane = tid & 63;
    const int W    = __builtin_amdgcn_readfirstlane(tid >> 6);   // 0..3
    const int q    = lane >> 4;
    const int b    = lane & 15;

    const int key = keys[g * 16 + b];
    const int ob  = key & 255;
    const int sl  = key >> 8;
    int tfin = sl - 1; if (tfin < 1) tfin = 1;

    int tmax = tfin;
    #pragma unroll
    for (int o = 1; o < 16; o <<= 1) {
        int c2 = __shfl_xor(tmax, o, 16); tmax = c2 > tmax ? c2 : tmax;
    }
    tmax = __builtin_amdgcn_readfirstlane(tmax);

    const int C  = (tmax + 4) >> 1;             // balanced cut (>=2)
    const int cb = tfin < C ? tfin : C;

    int cmax = cb, cmin = cb;
    #pragma unroll
    for (int o = 1; o < 16; o <<= 1) {
        int a = __shfl_xor(cmax, o, 16); cmax = a > cmax ? a : cmax;
        int b2 = __shfl_xor(cmin, o, 16); cmin = b2 < cmin ? b2 : cmin;
    }
    cmax = __builtin_amdgcn_readfirstlane(cmax);
    cmin = __builtin_amdgcn_readfirstlane(cmin);

    const int tb0 = (tmax + 4) & ~3;            // bwd start, == 0 mod 4

    // slot -> cg mapping: {W, others ascending}
    const int c1 = (W == 0) ? 1 : 0;
    const int c2 = (W <= 1) ? 2 : 1;
    const int c3 = (W <= 2) ? 3 : 2;
    const int o0 = (c1 * 64 + lane) * 8;
    const int o1 = (c2 * 64 + lane) * 8;
    const int o2 = (c3 * 64 + lane) * 8;
    const int ws = (W  * 64 + lane) * 8;

    // E fragments: af[m][i], slot i -> cg {W,c1,c2,c3};
    // j = 32W + 16m + b; k = 32c + 16*(jj>>2) + 4q + (jj&3) (verified)
    bf16x8 af[2][4];
    #pragma unroll
    for (int m = 0; m < 2; ++m) {
        const int j = 32 * W + 16 * m + b;
        #pragma unroll
        for (int i = 0; i < 4; ++i) {
            const int c = (i == 0) ? W : (i == 1) ? c1 : (i == 2) ? c2 : c3;
            #pragma unroll
            for (int jj = 0; jj < 8; ++jj) {
                int k = 32 * c + 16 * (jj >> 2) + 4 * q + (jj & 3);
                int idx = isf ? (k * TT + j) : (j * TT + k);
                float ev = __builtin_amdgcn_exp2f(trans[idx] * L2E);
                af[m][i][jj] = (short)(bfround(ev) >> 16);
            }
        }
    }

    const float* pu = inputs + (size_t)ob * LL * TT + 32 * W + q * 4;
    float Dacc = 0.f;
    float4 up[4][2];
    bf16x8 bs;

    if (tid < 16) sbuf[tid] = 1.0f;             // initial scale (buf 0)

    if (isf) {
        // init q0 = exp(in[0][j]) -> self frag + LDS buf0 (cb>=1: no init cap)
        float q0[2][4];
        #pragma unroll
        for (int m = 0; m < 2; ++m) {
            float4 v = *(const float4*)(pu + m * 16);
            q0[m][0] = __builtin_amdgcn_exp2f(v.x * L2E);
            q0[m][1] = __builtin_amdgcn_exp2f(v.y * L2E);
            q0[m][2] = __builtin_amdgcn_exp2f(v.z * L2E);
            q0[m][3] = __builtin_amdgcn_exp2f(v.w * L2E);
        }
        bfrw pk;
        pk.w[0] = pack2(q0[0][0], q0[0][1]);
        pk.w[1] = pack2(q0[0][2], q0[0][3]);
        pk.w[2] = pack2(q0[1][0], q0[1][1]);
        pk.w[3] = pack2(q0[1][2], q0[1][3]);
        bs = pk.v;
        *(bf16x8*)(fragls + ws) = pk.v;

        #pragma unroll
        for (int s = 1; s <= 4; ++s) {
            up[s & 3][0] = *(const float4*)(pu + (size_t)s * TT);
            up[s & 3][1] = *(const float4*)(pu + (size_t)s * TT + 16);
        }
        __syncthreads();

        for (int tb = 1; tb <= cmax; tb += 4) {
            phase<true,0>(tb+0, Dacc, up, af, bs, fragls, sbuf, pu, capl, dcap, o0,o1,o2,ws, cb, tfin, W, q, b);
            phase<true,1>(tb+1, Dacc, up, af, bs, fragls, sbuf, pu, capl, dcap, o0,o1,o2,ws, cb, tfin, W, q, b);
            phase<true,2>(tb+2, Dacc, up, af, bs, fragls, sbuf, pu, capl, dcap, o0,o1,o2,ws, cb, tfin, W, q, b);
            phase<true,3>(tb+3, Dacc, up, af, bs, fragls, sbuf, pu, capl, dcap, o0,o1,o2,ws, cb, tfin, W, q, b);
        }
    } else {
        // init w = 1.0; batches with cb == tfin capture ones / Dr = 0 here
        bfrw pk;
        pk.w[0] = pk.w[1] = pk.w[2] = pk.w[3] = 0x3F803F80u;
        bs = pk.v;
        *(bf16x8*)(fragls + ws) = pk.v;
        if (cb == tfin) {
            float4 one4 = {1.f, 1.f, 1.f, 1.f};
            *(float4*)(capl + b * TT + 32 * W + q * 4)      = one4;
            *(float4*)(capl + b * TT + 32 * W + 16 + q * 4) = one4;
            if (W == 0 && q == 0) dcap[b] = 0.f;
        }
        #pragma unroll
        for (int ph = 0; ph < 4; ++ph) {
            int ui = tb0 - 1 - ph;
            ui = ui > LL - 1 ? LL - 1 : (ui < 0 ? 0 : ui);
            up[(3 - ph) & 3][0] = *(const float4*)(pu + (size_t)ui * TT);
            up[(3 - ph) & 3][1] = *(const float4*)(pu + (size_t)ui * TT + 16);
        }
        __syncthreads();

        for (int tb = tb0; tb > cmin; tb -= 4) {
            phase<false,0>(tb-0, Dacc, up, af, bs, fragls, sbuf, pu, capl, dcap, o0,o1,o2,ws, cb, tfin, W, q, b);
            phase<false,1>(tb-1, Dacc, up, af, bs, fragls, sbuf, pu, capl, dcap, o0,o1,o2,ws, cb, tfin, W, q, b);
            phase<false,2>(tb-2, Dacc, up, af, bs, fragls, sbuf, pu, capl, dcap, o0,o1,o2,ws, cb, tfin, W, q, b);
            phase<false,3>(tb-3, Dacc, up, af, bs, fragls, sbuf, pu, capl, dcap, o0,o1,o2,ws, cb, tfin, W, q, b);
        }
    }

    // copy captures out (last lds_barrier synced + drained everything)
    float* gout = isf ? qcap : rcap;
    #pragma unroll
    for (int i = 0; i < 2; ++i) {
        float4 v = *(const float4*)(capl + i * 1024 + tid * 4);
        *(float4*)(gout + (size_t)g * 16 * TT + i * 1024 + tid * 4) = v;
    }
    if (tid < 16) (isf ? dqv : drv)[g * 16 + tid] = dcap[tid];
}

__global__ void crf_comb(const float* __restrict__ qcap, const float* __restrict__ rcap,
                         const float* __restrict__ dqv, const float* __restrict__ drv,
                         const int* __restrict__ perm, const float* __restrict__ scorebuf,
                         float* __restrict__ out) {
    const int tid = threadIdx.x;
    const int r16 = tid >> 4, part = tid & 15;
    const int rank = blockIdx.x * 16 + r16;
    const float* qc = qcap + rank * TT + part * 8;
    const float* rc = rcap + rank * TT + part * 8;
    float4 a0 = *(const float4*)(qc);
    float4 a1 = *(const float4*)(qc + 4);
    float4 b0 = *(const float4*)(rc);
    float4 b1 = *(const float4*)(rc + 4);
    float s = a0.x*b0.x + a0.y*b0.y + a0.z*b0.z + a0.w*b0.w
            + a1.x*b1.x + a1.y*b1.y + a1.z*b1.z + a1.w*b1.w;
    #pragma unroll
    for (int o = 1; o < 16; o <<= 1) s += __shfl_xor(s, o, 16);
    if (part == 0) {
        int ob = perm[rank];
        float logZ = LN2f * (__builtin_amdgcn_logf(s) + dqv[rank] + drv[rank]);
        out[ob] = scorebuf[ob] - logZ;
    }
}

extern "C" void kernel_launch(void* const* d_in, const int* in_sizes, int n_in,
                              void* d_out, int out_size, void* d_ws, size_t ws_size,
                              hipStream_t stream) {
    const float* inputs = (const float*)d_in[0];
    const int*   tags   = (const int*)d_in[1];
    const int*   slens  = (const int*)d_in[2];
    const float* trans  = (const float*)d_in[3];
    float* out = (float*)d_out;

    float* qcap = (float*)d_ws;            // 256*128 f32
    float* rcap = qcap + 32768;            // 256*128 f32
    float* dqv  = rcap + 32768;            // 256
    float* drv  = dqv + 256;               // 256
    int*   perm = (int*)(drv + 256);       // 256
    float* scorebuf = (float*)(perm + 256);// 256

    crf_scan<<<2 * NBLK + 64, 256, 0, stream>>>(inputs, tags, slens, trans,
                                                qcap, rcap, dqv, drv, perm, scorebuf);
    crf_comb<<<NBLK, 256, 0, stream>>>(qcap, rcap, dqv, drv, perm, scorebuf, out);
}